// Round 2
// baseline (1557.240 us; speedup 1.0000x reference)
//
#include <hip/hip_runtime.h>
#include <hip/hip_bf16.h>
#include <math.h>

#define CC0 2000
#define CC1 10000
#define CC2 50000
#define DH  1024
#define BATCH 4096
#define OUT_HEAD (CC0 + 2)

typedef __attribute__((ext_vector_type(4))) float  f32x4;
typedef __attribute__((ext_vector_type(8))) __bf16 bf16x8;
typedef __attribute__((ext_vector_type(8))) short  s16x8;

// ---------------- fp32 -> bf16 conversion ----------------
__global__ __launch_bounds__(256) void f2bf_kernel(const float4* __restrict__ in,
                                                   ushort4* __restrict__ out, int n4) {
    int i = blockIdx.x * blockDim.x + threadIdx.x;
    int stride = gridDim.x * blockDim.x;
    for (; i < n4; i += stride) {
        float4 v = in[i];
        ushort4 o;
        o.x = __builtin_bit_cast(unsigned short, (__bf16)v.x);
        o.y = __builtin_bit_cast(unsigned short, (__bf16)v.y);
        o.z = __builtin_bit_cast(unsigned short, (__bf16)v.z);
        o.w = __builtin_bit_cast(unsigned short, (__bf16)v.w);
        out[i] = o;
    }
}

// ---------------- zero row-sum accumulators ----------------
__global__ __launch_bounds__(256) void zero_kernel(float* __restrict__ a,
                                                   float* __restrict__ b, int n) {
    int i = blockIdx.x * blockDim.x + threadIdx.x;
    if (i < n) { a[i] = 0.f; b[i] = 0.f; }
}

// ---------------- generic bf16 MFMA GEMM: C[M,N] = A[M,K] * B[N,K]^T ----------------
// 64x64 block tile, 4 waves (2x2), each wave 32x32 via 2x2 mfma_16x16x32 fragments.
template <bool OUT_BF16, bool SUMEXP>
__global__ __launch_bounds__(256) void gemm64_kernel(
    const ushort* __restrict__ A, const ushort* __restrict__ B,
    void* __restrict__ Cp, int M, int N, int K, int ldC,
    float* __restrict__ rowsum)
{
    __shared__ ushort As[64][72];  // +8 pad: breaks 128B-stride bank conflict
    __shared__ ushort Bs[64][72];

    const int t  = threadIdx.x;
    const int bm = blockIdx.y * 64;
    const int bn = blockIdx.x * 64;
    const int lane = t & 63;
    const int w  = t >> 6;
    const int wr = w >> 1, wc = w & 1;
    const int lr = lane & 15;   // fragment row (A) / col (B,C)
    const int lg = lane >> 4;   // k-group (inputs) / row-group (C)

    f32x4 acc[2][2] = {};

    const int nkt = K / 64;
    for (int kt = 0; kt < nkt; ++kt) {
        const int k0 = kt * 64;
        // ---- stage 64x64 A and B tiles (each thread: 2x16B for A, 2x16B for B)
        #pragma unroll
        for (int i = 0; i < 2; ++i) {
            int c   = t + i * 256;       // 0..511
            int row = c >> 3;
            int col = (c & 7) * 8;
            s16x8 va = {};
            int gra = bm + row;
            if (gra < M) va = *(const s16x8*)(A + (size_t)gra * K + k0 + col);
            *(s16x8*)&As[row][col] = va;
            s16x8 vb = {};
            int grb = bn + row;
            if (grb < N) vb = *(const s16x8*)(B + (size_t)grb * K + k0 + col);
            *(s16x8*)&Bs[row][col] = vb;
        }
        __syncthreads();
        // ---- 2 K-steps of 32, 4 mfmas each
        #pragma unroll
        for (int ks = 0; ks < 2; ++ks) {
            s16x8 a0 = *(const s16x8*)&As[wr * 32 +      lr][ks * 32 + lg * 8];
            s16x8 a1 = *(const s16x8*)&As[wr * 32 + 16 + lr][ks * 32 + lg * 8];
            s16x8 b0 = *(const s16x8*)&Bs[wc * 32 +      lr][ks * 32 + lg * 8];
            s16x8 b1 = *(const s16x8*)&Bs[wc * 32 + 16 + lr][ks * 32 + lg * 8];
            acc[0][0] = __builtin_amdgcn_mfma_f32_16x16x32_bf16(
                __builtin_bit_cast(bf16x8, a0), __builtin_bit_cast(bf16x8, b0), acc[0][0], 0, 0, 0);
            acc[0][1] = __builtin_amdgcn_mfma_f32_16x16x32_bf16(
                __builtin_bit_cast(bf16x8, a0), __builtin_bit_cast(bf16x8, b1), acc[0][1], 0, 0, 0);
            acc[1][0] = __builtin_amdgcn_mfma_f32_16x16x32_bf16(
                __builtin_bit_cast(bf16x8, a1), __builtin_bit_cast(bf16x8, b0), acc[1][0], 0, 0, 0);
            acc[1][1] = __builtin_amdgcn_mfma_f32_16x16x32_bf16(
                __builtin_bit_cast(bf16x8, a1), __builtin_bit_cast(bf16x8, b1), acc[1][1], 0, 0, 0);
        }
        __syncthreads();
    }

    // ---- epilogue: C[row][col], row = bm + wr*32 + mi*16 + lg*4 + r, col = bn + wc*32 + ni*16 + lr
    #pragma unroll
    for (int mi = 0; mi < 2; ++mi) {
        #pragma unroll
        for (int r = 0; r < 4; ++r) {
            const int row = bm + wr * 32 + mi * 16 + lg * 4 + r;
            float psum = 0.f;
            #pragma unroll
            for (int ni = 0; ni < 2; ++ni) {
                const int col = bn + wc * 32 + ni * 16 + lr;
                float v = acc[mi][ni][r];
                if (row < M && col < N) {
                    if (OUT_BF16)
                        ((ushort*)Cp)[(size_t)row * ldC + col] =
                            __builtin_bit_cast(unsigned short, (__bf16)v);
                    else
                        ((float*)Cp)[(size_t)row * ldC + col] = v;
                }
                if (SUMEXP) psum += __expf(v);   // logits are O(1): max-free LSE is safe
            }
            if (SUMEXP) {
                #pragma unroll
                for (int m = 1; m < 16; m <<= 1) psum += __shfl_xor(psum, m, 64);
                if (lr == 0) atomicAdd(&rowsum[row], psum);
            }
        }
    }
}

// ---------------- head log-softmax: one block per row ----------------
__global__ __launch_bounds__(256) void head_lsm_kernel(
    const float* __restrict__ HL, const float* __restrict__ bh,
    float* __restrict__ out, float* __restrict__ s01)
{
    const int row = blockIdx.x;
    const float* L = HL + (size_t)row * OUT_HEAD;
    const int t = threadIdx.x;
    __shared__ float red[4];

    float m = -1e30f;
    for (int i = t; i < OUT_HEAD; i += 256) m = fmaxf(m, L[i] + bh[i]);
    #pragma unroll
    for (int s = 1; s < 64; s <<= 1) m = fmaxf(m, __shfl_xor(m, s, 64));
    if ((t & 63) == 0) red[t >> 6] = m;
    __syncthreads();
    m = fmaxf(fmaxf(red[0], red[1]), fmaxf(red[2], red[3]));

    float sum = 0.f;
    for (int i = t; i < OUT_HEAD; i += 256) sum += __expf(L[i] + bh[i] - m);
    #pragma unroll
    for (int s = 1; s < 64; s <<= 1) sum += __shfl_xor(sum, s, 64);
    __syncthreads();
    if ((t & 63) == 0) red[t >> 6] = sum;
    __syncthreads();
    const float lse = m + logf(red[0] + red[1] + red[2] + red[3]);

    float* orow = out + (size_t)row * CC2;
    for (int i = t; i < CC0; i += 256) orow[i] = L[i] + bh[i] - lse;
    if (t == 0) {
        s01[2 * row + 0] = L[CC0 + 0] + bh[CC0 + 0] - lse;
        s01[2 * row + 1] = L[CC0 + 1] + bh[CC0 + 1] - lse;
    }
}

// ---------------- finalize tails: out = raw - log(rowsum) + cluster_logprob ----------------
__global__ __launch_bounds__(256) void finalize_kernel(
    float* __restrict__ outb, int ncols4, const float* __restrict__ rowsum,
    const float* __restrict__ s01, int which)
{
    const int row = blockIdx.y;
    const float add = s01[2 * row + which] - logf(rowsum[row]);
    float4* p = (float4*)(outb + (size_t)row * CC2);
    const int c = blockIdx.x * blockDim.x + threadIdx.x;
    if (c < ncols4) {
        float4 v = p[c];
        v.x += add; v.y += add; v.z += add; v.w += add;
        p[c] = v;
    }
}

// ---------------- launch ----------------
extern "C" void kernel_launch(void* const* d_in, const int* in_sizes, int n_in,
                              void* d_out, int out_size, void* d_ws, size_t ws_size,
                              hipStream_t stream) {
    const float* x   = (const float*)d_in[0];
    const float* Wh  = (const float*)d_in[1];
    const float* bh  = (const float*)d_in[2];
    const float* W0a = (const float*)d_in[3];
    const float* W0b = (const float*)d_in[4];
    const float* W1a = (const float*)d_in[5];
    const float* W1b = (const float*)d_in[6];
    float* out = (float*)d_out;
    char*  ws  = (char*)d_ws;

    size_t off = 0;
    auto alloc = [&](size_t bytes) { size_t o = off; off += (bytes + 255) & ~(size_t)255; return o; };
    ushort* x_bf   = (ushort*)(ws + alloc((size_t)BATCH * DH * 2));
    ushort* Wh_bf  = (ushort*)(ws + alloc((size_t)OUT_HEAD * DH * 2));
    ushort* W0a_bf = (ushort*)(ws + alloc((size_t)DH * DH * 2));
    ushort* W0b_bf = (ushort*)(ws + alloc((size_t)(CC1 - CC0) * DH * 2));
    ushort* W1a_bf = (ushort*)(ws + alloc((size_t)256 * DH * 2));
    ushort* W1b_bf = (ushort*)(ws + alloc((size_t)(CC2 - CC1) * 256 * 2));
    ushort* h0_bf  = (ushort*)(ws + alloc((size_t)BATCH * DH * 2));
    ushort* h1_bf  = (ushort*)(ws + alloc((size_t)BATCH * 256 * 2));
    float*  headL  = (float*)(ws + alloc((size_t)BATCH * OUT_HEAD * 4));
    float*  s01    = (float*)(ws + alloc((size_t)BATCH * 2 * 4));
    float*  rs0    = (float*)(ws + alloc((size_t)BATCH * 4));
    float*  rs1    = (float*)(ws + alloc((size_t)BATCH * 4));

    auto cvt = [&](const float* in, ushort* o, size_t n) {
        int n4 = (int)(n / 4);
        int blocks = (n4 + 255) / 256;
        if (blocks > 2048) blocks = 2048;
        f2bf_kernel<<<blocks, 256, 0, stream>>>((const float4*)in, (ushort4*)o, n4);
    };
    cvt(x,   x_bf,   (size_t)BATCH * DH);
    cvt(Wh,  Wh_bf,  (size_t)OUT_HEAD * DH);
    cvt(W0a, W0a_bf, (size_t)DH * DH);
    cvt(W0b, W0b_bf, (size_t)(CC1 - CC0) * DH);
    cvt(W1a, W1a_bf, (size_t)256 * DH);
    cvt(W1b, W1b_bf, (size_t)(CC2 - CC1) * 256);

    zero_kernel<<<(BATCH + 255) / 256, 256, 0, stream>>>(rs0, rs1, BATCH);

    // h0 = x @ W0a^T  (bf16 out), h1 = x @ W1a^T (bf16 out)
    gemm64_kernel<true, false><<<dim3(DH / 64, BATCH / 64), 256, 0, stream>>>(
        x_bf, W0a_bf, h0_bf, BATCH, DH, DH, DH, nullptr);
    gemm64_kernel<true, false><<<dim3(256 / 64, BATCH / 64), 256, 0, stream>>>(
        x_bf, W1a_bf, h1_bf, BATCH, 256, DH, 256, nullptr);
    // head logits (fp32 out, ws)
    gemm64_kernel<false, false><<<dim3((OUT_HEAD + 63) / 64, BATCH / 64), 256, 0, stream>>>(
        x_bf, Wh_bf, headL, BATCH, OUT_HEAD, DH, OUT_HEAD, nullptr);
    // head log-softmax -> out[:, :2000] and cluster scalars
    head_lsm_kernel<<<BATCH, 256, 0, stream>>>(headL, bh, out, s01);
    // tail logits straight into out, with fused row sum-of-exp
    gemm64_kernel<false, true><<<dim3((CC1 - CC0) / 64, BATCH / 64), 256, 0, stream>>>(
        h0_bf, W0b_bf, out + CC0, BATCH, CC1 - CC0, DH, CC2, rs0);
    gemm64_kernel<false, true><<<dim3((CC2 - CC1) / 64, BATCH / 64), 256, 0, stream>>>(
        h1_bf, W1b_bf, out + CC1, BATCH, CC2 - CC1, 256, CC2, rs1);
    // normalize tails in place: tail0 = 8000 floats = 2000 float4s, tail1 = 40000 floats = 10000 float4s
    finalize_kernel<<<dim3((2000 + 255) / 256, BATCH), 256, 0, stream>>>(
        out + CC0, 2000, rs0, s01, 0);
    finalize_kernel<<<dim3((10000 + 255) / 256, BATCH), 256, 0, stream>>>(
        out + CC1, 10000, rs1, s01, 1);
}

// Round 3
// 922.121 us; speedup vs baseline: 1.6888x; 1.6888x over previous
//
#include <hip/hip_runtime.h>
#include <hip/hip_bf16.h>
#include <math.h>

#define CC0 2000
#define CC1 10000
#define CC2 50000
#define DH  1024
#define BATCH 4096
#define OUT_HEAD (CC0 + 2)

typedef __attribute__((ext_vector_type(4))) float  f32x4;
typedef __attribute__((ext_vector_type(8))) __bf16 bf16x8;
typedef __attribute__((ext_vector_type(8))) short  s16x8;

__device__ __forceinline__ void gload_lds16(const void* g, void* l) {
    __builtin_amdgcn_global_load_lds(
        (const __attribute__((address_space(1))) void*)g,
        (__attribute__((address_space(3))) void*)l, 16, 0, 0);
}

// ---------------- fp32 -> bf16 conversion with zero-padding ----------------
__global__ __launch_bounds__(256) void f2bf_pad_kernel(const float4* __restrict__ in,
                                                       ushort4* __restrict__ out,
                                                       int n4_src, int n4_dst) {
    int i = blockIdx.x * blockDim.x + threadIdx.x;
    int stride = gridDim.x * blockDim.x;
    for (; i < n4_dst; i += stride) {
        ushort4 o = {0, 0, 0, 0};
        if (i < n4_src) {
            float4 v = in[i];
            o.x = __builtin_bit_cast(unsigned short, (__bf16)v.x);
            o.y = __builtin_bit_cast(unsigned short, (__bf16)v.y);
            o.z = __builtin_bit_cast(unsigned short, (__bf16)v.z);
            o.w = __builtin_bit_cast(unsigned short, (__bf16)v.w);
        }
        out[i] = o;
    }
}

// ---------------- zero row-sum accumulators ----------------
__global__ __launch_bounds__(256) void zero_kernel(float* __restrict__ a,
                                                   float* __restrict__ b, int n) {
    int i = blockIdx.x * blockDim.x + threadIdx.x;
    if (i < n) { a[i] = 0.f; b[i] = 0.f; }
}

// ---------------- 128x128 MFMA GEMM (m97 structure): C[M,N] = A[M,K] * B[N,K]^T ----
// 4 waves (2x2), each wave a 64x64 sub-tile via 4x4 mfma_16x16x32 fragments.
// BK=64, single LDS buffer, global_load_lds width-16 staging, linear LDS layout.
// Requires: M % 128 == 0, K % 64 == 0, B padded (zero) to Npad = 128*gridDim.x rows.
template <bool OUT_BF16, bool SUMEXP>
__global__ __launch_bounds__(256) void gemm128_kernel(
    const ushort* __restrict__ A, const ushort* __restrict__ B,
    void* __restrict__ Cp, int M, int N, int K, int ldC,
    float* __restrict__ rowsum)
{
    __shared__ ushort As[128 * 64];
    __shared__ ushort Bs[128 * 64];

    // bijective XCD swizzle (all launches have nwg % 8 == 0)
    const int nwg = gridDim.x * gridDim.y;
    const int q = nwg >> 3;
    int bid = blockIdx.y * gridDim.x + blockIdx.x;
    bid = (bid & 7) * q + (bid >> 3);
    const int bx = bid % gridDim.x;
    const int by = bid / gridDim.x;

    const int t = threadIdx.x;
    const int lane = t & 63;
    const int w = t >> 6;
    const int wr = w >> 1, wc = w & 1;
    const int lr = lane & 15;       // input frag row / C col
    const int lg = lane >> 4;       // input k-group / C row-group
    const int bm = by * 128;
    const int bn = bx * 128;

    const int lrow = lane >> 3;          // 0..7 within a 1KB segment
    const int lcol = (lane & 7) * 8;     // element col within BK=64

    f32x4 acc[4][4] = {};

    for (int k0 = 0; k0 < K; k0 += 64) {
        #pragma unroll
        for (int i = 0; i < 4; ++i) {
            const int seg = w * 4 + i;                // 0..15, wave-uniform
            const int row = seg * 8 + lrow;           // 0..127
            gload_lds16(A + (size_t)(bm + row) * K + k0 + lcol, &As[seg * 512]);
            gload_lds16(B + (size_t)(bn + row) * K + k0 + lcol, &Bs[seg * 512]);
        }
        __syncthreads();
        #pragma unroll
        for (int ks = 0; ks < 2; ++ks) {
            s16x8 af[4], bfr[4];
            #pragma unroll
            for (int m = 0; m < 4; ++m)
                af[m] = *(const s16x8*)&As[(wr * 64 + m * 16 + lr) * 64 + ks * 32 + lg * 8];
            #pragma unroll
            for (int n = 0; n < 4; ++n)
                bfr[n] = *(const s16x8*)&Bs[(wc * 64 + n * 16 + lr) * 64 + ks * 32 + lg * 8];
            #pragma unroll
            for (int m = 0; m < 4; ++m)
                #pragma unroll
                for (int n = 0; n < 4; ++n)
                    acc[m][n] = __builtin_amdgcn_mfma_f32_16x16x32_bf16(
                        __builtin_bit_cast(bf16x8, af[m]),
                        __builtin_bit_cast(bf16x8, bfr[n]), acc[m][n], 0, 0, 0);
        }
        __syncthreads();
    }

    // epilogue: row = bm + wr*64 + m*16 + lg*4 + r;  col = bn + wc*64 + n*16 + lr
    #pragma unroll
    for (int m = 0; m < 4; ++m) {
        #pragma unroll
        for (int r = 0; r < 4; ++r) {
            const int row = bm + wr * 64 + m * 16 + lg * 4 + r;
            float psum = 0.f;
            #pragma unroll
            for (int n = 0; n < 4; ++n) {
                const int col = bn + wc * 64 + n * 16 + lr;
                float v = acc[m][n][r];
                if (col < N) {
                    if (OUT_BF16)
                        ((ushort*)Cp)[(size_t)row * ldC + col] =
                            __builtin_bit_cast(unsigned short, (__bf16)v);
                    else
                        ((float*)Cp)[(size_t)row * ldC + col] = v;
                    if (SUMEXP) psum += __expf(v);  // logits O(1): max-free LSE safe
                }
            }
            if (SUMEXP) {
                #pragma unroll
                for (int mm = 1; mm < 16; mm <<= 1) psum += __shfl_xor(psum, mm, 64);
                if (lr == 0) atomicAdd(&rowsum[row], psum);
            }
        }
    }
}

// ---------------- head log-softmax: one block per row ----------------
__global__ __launch_bounds__(256) void head_lsm_kernel(
    const float* __restrict__ HL, const float* __restrict__ bh,
    float* __restrict__ out, float* __restrict__ s01)
{
    const int row = blockIdx.x;
    const float* L = HL + (size_t)row * OUT_HEAD;
    const int t = threadIdx.x;
    __shared__ float red[4];

    float m = -1e30f;
    for (int i = t; i < OUT_HEAD; i += 256) m = fmaxf(m, L[i] + bh[i]);
    #pragma unroll
    for (int s = 1; s < 64; s <<= 1) m = fmaxf(m, __shfl_xor(m, s, 64));
    if ((t & 63) == 0) red[t >> 6] = m;
    __syncthreads();
    m = fmaxf(fmaxf(red[0], red[1]), fmaxf(red[2], red[3]));

    float sum = 0.f;
    for (int i = t; i < OUT_HEAD; i += 256) sum += __expf(L[i] + bh[i] - m);
    #pragma unroll
    for (int s = 1; s < 64; s <<= 1) sum += __shfl_xor(sum, s, 64);
    __syncthreads();
    if ((t & 63) == 0) red[t >> 6] = sum;
    __syncthreads();
    const float lse = m + logf(red[0] + red[1] + red[2] + red[3]);

    float* orow = out + (size_t)row * CC2;
    for (int i = t; i < CC0; i += 256) orow[i] = L[i] + bh[i] - lse;
    if (t == 0) {
        s01[2 * row + 0] = L[CC0 + 0] + bh[CC0 + 0] - lse;
        s01[2 * row + 1] = L[CC0 + 1] + bh[CC0 + 1] - lse;
    }
}

// ---------------- finalize tails: out += cluster_logprob - log(rowsum) ----------------
__global__ __launch_bounds__(256) void finalize_kernel(
    float* __restrict__ outb, int ncols4, const float* __restrict__ rowsum,
    const float* __restrict__ s01, int which)
{
    const int row = blockIdx.y;
    const float add = s01[2 * row + which] - logf(rowsum[row]);
    float4* p = (float4*)(outb + (size_t)row * CC2);
    const int c = blockIdx.x * blockDim.x + threadIdx.x;
    if (c < ncols4) {
        float4 v = p[c];
        v.x += add; v.y += add; v.z += add; v.w += add;
        p[c] = v;
    }
}

// ---------------- launch ----------------
extern "C" void kernel_launch(void* const* d_in, const int* in_sizes, int n_in,
                              void* d_out, int out_size, void* d_ws, size_t ws_size,
                              hipStream_t stream) {
    const float* x   = (const float*)d_in[0];
    const float* Wh  = (const float*)d_in[1];
    const float* bh  = (const float*)d_in[2];
    const float* W0a = (const float*)d_in[3];
    const float* W0b = (const float*)d_in[4];
    const float* W1a = (const float*)d_in[5];
    const float* W1b = (const float*)d_in[6];
    float* out = (float*)d_out;
    char*  ws  = (char*)d_ws;

    // padded row counts (multiples of 128)
    const int NH_P  = 2048;    // head rows (2002 -> 2048)
    const int N0_P  = 8064;    // tail0 proj rows (8000 -> 8064)
    const int N1_P  = 40064;   // tail1 proj rows (40000 -> 40064)

    size_t off = 0;
    auto alloc = [&](size_t bytes) { size_t o = off; off += (bytes + 255) & ~(size_t)255; return o; };
    ushort* x_bf   = (ushort*)(ws + alloc((size_t)BATCH * DH * 2));
    ushort* Wh_bf  = (ushort*)(ws + alloc((size_t)NH_P * DH * 2));
    ushort* W0a_bf = (ushort*)(ws + alloc((size_t)DH * DH * 2));
    ushort* W0b_bf = (ushort*)(ws + alloc((size_t)N0_P * DH * 2));
    ushort* W1a_bf = (ushort*)(ws + alloc((size_t)256 * DH * 2));
    ushort* W1b_bf = (ushort*)(ws + alloc((size_t)N1_P * 256 * 2));
    ushort* h0_bf  = (ushort*)(ws + alloc((size_t)BATCH * DH * 2));
    ushort* h1_bf  = (ushort*)(ws + alloc((size_t)BATCH * 256 * 2));
    float*  headL  = (float*)(ws + alloc((size_t)BATCH * OUT_HEAD * 4));
    float*  s01    = (float*)(ws + alloc((size_t)BATCH * 2 * 4));
    float*  rs0    = (float*)(ws + alloc((size_t)BATCH * 4));
    float*  rs1    = (float*)(ws + alloc((size_t)BATCH * 4));

    auto cvt = [&](const float* in, ushort* o, size_t n_src, size_t n_dst) {
        int n4s = (int)(n_src / 4), n4d = (int)(n_dst / 4);
        int blocks = (n4d + 255) / 256;
        if (blocks > 2048) blocks = 2048;
        f2bf_pad_kernel<<<blocks, 256, 0, stream>>>((const float4*)in, (ushort4*)o, n4s, n4d);
    };
    cvt(x,   x_bf,   (size_t)BATCH * DH,        (size_t)BATCH * DH);
    cvt(Wh,  Wh_bf,  (size_t)OUT_HEAD * DH,     (size_t)NH_P * DH);
    cvt(W0a, W0a_bf, (size_t)DH * DH,           (size_t)DH * DH);
    cvt(W0b, W0b_bf, (size_t)(CC1 - CC0) * DH,  (size_t)N0_P * DH);
    cvt(W1a, W1a_bf, (size_t)256 * DH,          (size_t)256 * DH);
    cvt(W1b, W1b_bf, (size_t)(CC2 - CC1) * 256, (size_t)N1_P * 256);

    zero_kernel<<<(BATCH + 255) / 256, 256, 0, stream>>>(rs0, rs1, BATCH);

    // h0 = x @ W0a^T (bf16), h1 = x @ W1a^T (bf16)
    gemm128_kernel<true, false><<<dim3(DH / 128, BATCH / 128), 256, 0, stream>>>(
        x_bf, W0a_bf, h0_bf, BATCH, DH, DH, DH, nullptr);
    gemm128_kernel<true, false><<<dim3(256 / 128, BATCH / 128), 256, 0, stream>>>(
        x_bf, W1a_bf, h1_bf, BATCH, 256, DH, 256, nullptr);
    // head logits (fp32, ws)
    gemm128_kernel<false, false><<<dim3(NH_P / 128, BATCH / 128), 256, 0, stream>>>(
        x_bf, Wh_bf, headL, BATCH, OUT_HEAD, DH, OUT_HEAD, nullptr);
    // head log-softmax -> out[:, :2000] + cluster scalars
    head_lsm_kernel<<<BATCH, 256, 0, stream>>>(headL, bh, out, s01);
    // tail logits into out with fused row sum-of-exp
    gemm128_kernel<false, true><<<dim3(N0_P / 128, BATCH / 128), 256, 0, stream>>>(
        h0_bf, W0b_bf, out + CC0, BATCH, CC1 - CC0, DH, CC2, rs0);
    gemm128_kernel<false, true><<<dim3(N1_P / 128, BATCH / 128), 256, 0, stream>>>(
        h1_bf, W1b_bf, out + CC1, BATCH, CC2 - CC1, 256, CC2, rs1);
    // normalize tails in place (tail0: 2000 float4 cols, tail1: 10000 float4 cols)
    finalize_kernel<<<dim3((2000 + 255) / 256, BATCH), 256, 0, stream>>>(
        out + CC0, 2000, rs0, s01, 0);
    finalize_kernel<<<dim3((10000 + 255) / 256, BATCH), 256, 0, stream>>>(
        out + CC1, 10000, rs1, s01, 1);
}

// Round 4
// 802.894 us; speedup vs baseline: 1.9395x; 1.1485x over previous
//
#include <hip/hip_runtime.h>
#include <hip/hip_bf16.h>
#include <math.h>

#define CC0 2000
#define CC1 10000
#define CC2 50000
#define DH  1024
#define BATCH 4096
#define OUT_HEAD (CC0 + 2)

typedef __attribute__((ext_vector_type(4))) float  f32x4;
typedef __attribute__((ext_vector_type(8))) __bf16 bf16x8;
typedef __attribute__((ext_vector_type(8))) short  s16x8;

__device__ __forceinline__ void gload_lds16(const void* g, void* l) {
    __builtin_amdgcn_global_load_lds(
        (const __attribute__((address_space(1))) void*)g,
        (__attribute__((address_space(3))) void*)l, 16, 0, 0);
}

// ---------------- fp32 -> bf16 conversion with zero-padding ----------------
__global__ __launch_bounds__(256) void f2bf_pad_kernel(const float4* __restrict__ in,
                                                       ushort4* __restrict__ out,
                                                       int n4_src, int n4_dst) {
    int i = blockIdx.x * blockDim.x + threadIdx.x;
    int stride = gridDim.x * blockDim.x;
    for (; i < n4_dst; i += stride) {
        ushort4 o = {0, 0, 0, 0};
        if (i < n4_src) {
            float4 v = in[i];
            o.x = __builtin_bit_cast(unsigned short, (__bf16)v.x);
            o.y = __builtin_bit_cast(unsigned short, (__bf16)v.y);
            o.z = __builtin_bit_cast(unsigned short, (__bf16)v.z);
            o.w = __builtin_bit_cast(unsigned short, (__bf16)v.w);
        }
        out[i] = o;
    }
}

// ---------------- zero row-sum accumulators ----------------
__global__ __launch_bounds__(256) void zero_kernel(float* __restrict__ a,
                                                   float* __restrict__ b, int n) {
    int i = blockIdx.x * blockDim.x + threadIdx.x;
    if (i < n) { a[i] = 0.f; b[i] = 0.f; }
}

// ---------------- 128x128 MFMA GEMM (m97 structure): C[M,N] = A[M,K] * B[N,K]^T ----
// 4 waves (2x2), each wave a 64x64 sub-tile via 4x4 mfma_16x16x32 fragments.
// BK=64, single LDS buffer, global_load_lds width-16 staging, linear LDS layout.
// Requires: M % 128 == 0, K % 64 == 0, B zero-padded to 128*gridDim.x rows.
template <bool OUT_BF16, bool SUMEXP>
__global__ __launch_bounds__(256) void gemm128_kernel(
    const ushort* __restrict__ A, const ushort* __restrict__ B,
    void* __restrict__ Cp, int M, int N, int K, int ldC,
    float* __restrict__ rowsum)
{
    __shared__ ushort As[128 * 64];
    __shared__ ushort Bs[128 * 64];

    // bijective XCD swizzle (all launches have nwg % 8 == 0)
    const int nwg = gridDim.x * gridDim.y;
    const int q = nwg >> 3;
    int bid = blockIdx.y * gridDim.x + blockIdx.x;
    bid = (bid & 7) * q + (bid >> 3);
    const int bx = bid % gridDim.x;
    const int by = bid / gridDim.x;

    const int t = threadIdx.x;
    const int lane = t & 63;
    const int w = t >> 6;
    const int wr = w >> 1, wc = w & 1;
    const int lr = lane & 15;       // input frag row / C col
    const int lg = lane >> 4;       // input k-group / C row-group
    const int bm = by * 128;
    const int bn = bx * 128;

    const int lrow = lane >> 3;          // 0..7 within a 1KB segment
    const int lcol = (lane & 7) * 8;     // element col within BK=64

    f32x4 acc[4][4] = {};

    for (int k0 = 0; k0 < K; k0 += 64) {
        #pragma unroll
        for (int i = 0; i < 4; ++i) {
            const int seg = w * 4 + i;                // 0..15, wave-uniform
            const int row = seg * 8 + lrow;           // 0..127
            gload_lds16(A + (size_t)(bm + row) * K + k0 + lcol, &As[seg * 512]);
            gload_lds16(B + (size_t)(bn + row) * K + k0 + lcol, &Bs[seg * 512]);
        }
        __syncthreads();
        #pragma unroll
        for (int ks = 0; ks < 2; ++ks) {
            s16x8 af[4], bfr[4];
            #pragma unroll
            for (int m = 0; m < 4; ++m)
                af[m] = *(const s16x8*)&As[(wr * 64 + m * 16 + lr) * 64 + ks * 32 + lg * 8];
            #pragma unroll
            for (int n = 0; n < 4; ++n)
                bfr[n] = *(const s16x8*)&Bs[(wc * 64 + n * 16 + lr) * 64 + ks * 32 + lg * 8];
            #pragma unroll
            for (int m = 0; m < 4; ++m)
                #pragma unroll
                for (int n = 0; n < 4; ++n)
                    acc[m][n] = __builtin_amdgcn_mfma_f32_16x16x32_bf16(
                        __builtin_bit_cast(bf16x8, af[m]),
                        __builtin_bit_cast(bf16x8, bfr[n]), acc[m][n], 0, 0, 0);
        }
        __syncthreads();
    }

    // epilogue: row = bm + wr*64 + m*16 + lg*4 + r;  col = bn + wc*64 + n*16 + lr
    #pragma unroll
    for (int m = 0; m < 4; ++m) {
        #pragma unroll
        for (int r = 0; r < 4; ++r) {
            const int row = bm + wr * 64 + m * 16 + lg * 4 + r;
            float psum = 0.f;
            #pragma unroll
            for (int n = 0; n < 4; ++n) {
                const int col = bn + wc * 64 + n * 16 + lr;
                float v = acc[m][n][r];
                if (col < N) {
                    if (OUT_BF16)
                        ((ushort*)Cp)[(size_t)row * ldC + col] =
                            __builtin_bit_cast(unsigned short, (__bf16)v);
                    else
                        ((float*)Cp)[(size_t)row * ldC + col] = v;
                    if (SUMEXP) psum += __expf(v);  // logits O(1): max-free LSE safe
                }
            }
            if (SUMEXP) {
                #pragma unroll
                for (int mm = 1; mm < 16; mm <<= 1) psum += __shfl_xor(psum, mm, 64);
                if (lr == 0) atomicAdd(&rowsum[row], psum);
            }
        }
    }
}

// ---------------- head log-softmax: one block per row ----------------
__global__ __launch_bounds__(256) void head_lsm_kernel(
    const float* __restrict__ HL, const float* __restrict__ bh,
    float* __restrict__ out, float* __restrict__ s01)
{
    const int row = blockIdx.x;
    const float* L = HL + (size_t)row * OUT_HEAD;
    const int t = threadIdx.x;
    __shared__ float red[4];

    float m = -1e30f;
    for (int i = t; i < OUT_HEAD; i += 256) m = fmaxf(m, L[i] + bh[i]);
    #pragma unroll
    for (int s = 1; s < 64; s <<= 1) m = fmaxf(m, __shfl_xor(m, s, 64));
    if ((t & 63) == 0) red[t >> 6] = m;
    __syncthreads();
    m = fmaxf(fmaxf(red[0], red[1]), fmaxf(red[2], red[3]));

    float sum = 0.f;
    for (int i = t; i < OUT_HEAD; i += 256) sum += __expf(L[i] + bh[i] - m);
    #pragma unroll
    for (int s = 1; s < 64; s <<= 1) sum += __shfl_xor(sum, s, 64);
    __syncthreads();
    if ((t & 63) == 0) red[t >> 6] = sum;
    __syncthreads();
    const float lse = m + logf(red[0] + red[1] + red[2] + red[3]);

    float* orow = out + (size_t)row * CC2;
    for (int i = t; i < CC0; i += 256) orow[i] = L[i] + bh[i] - lse;
    if (t == 0) {
        s01[2 * row + 0] = L[CC0 + 0] + bh[CC0 + 0] - lse;
        s01[2 * row + 1] = L[CC0 + 1] + bh[CC0 + 1] - lse;
    }
}

// ---------------- finalize tails from bf16 logits: out = bf16logit + (s01 - log(rowsum)) ----
// ncols8 = N/8 (N % 8 == 0). Reads ushort8 (16B), writes 2x float4.
__global__ __launch_bounds__(256) void finalize_bf16_kernel(
    const ushort* __restrict__ Lg, int ldL, int ncols8,
    float* __restrict__ outb, const float* __restrict__ rowsum,
    const float* __restrict__ s01, int which)
{
    const int row = blockIdx.y;
    const float add = s01[2 * row + which] - logf(rowsum[row]);
    const int c = blockIdx.x * blockDim.x + threadIdx.x;
    if (c >= ncols8) return;
    s16x8 v = *(const s16x8*)(Lg + (size_t)row * ldL + c * 8);
    float* o = outb + (size_t)row * CC2 + c * 8;
    float4 o0, o1;
    o0.x = __builtin_bit_cast(float, (unsigned)(unsigned short)v[0] << 16) + add;
    o0.y = __builtin_bit_cast(float, (unsigned)(unsigned short)v[1] << 16) + add;
    o0.z = __builtin_bit_cast(float, (unsigned)(unsigned short)v[2] << 16) + add;
    o0.w = __builtin_bit_cast(float, (unsigned)(unsigned short)v[3] << 16) + add;
    o1.x = __builtin_bit_cast(float, (unsigned)(unsigned short)v[4] << 16) + add;
    o1.y = __builtin_bit_cast(float, (unsigned)(unsigned short)v[5] << 16) + add;
    o1.z = __builtin_bit_cast(float, (unsigned)(unsigned short)v[6] << 16) + add;
    o1.w = __builtin_bit_cast(float, (unsigned)(unsigned short)v[7] << 16) + add;
    *(float4*)o = o0;
    *(float4*)(o + 4) = o1;
}

// ---------------- launch ----------------
extern "C" void kernel_launch(void* const* d_in, const int* in_sizes, int n_in,
                              void* d_out, int out_size, void* d_ws, size_t ws_size,
                              hipStream_t stream) {
    const float* x   = (const float*)d_in[0];
    const float* Wh  = (const float*)d_in[1];
    const float* bh  = (const float*)d_in[2];
    const float* W0a = (const float*)d_in[3];
    const float* W0b = (const float*)d_in[4];
    const float* W1a = (const float*)d_in[5];
    const float* W1b = (const float*)d_in[6];
    float* out = (float*)d_out;
    char*  ws  = (char*)d_ws;

    // padded row counts (multiples of 128)
    const int NH_P  = 2048;    // head rows (2002 -> 2048)
    const int N0_P  = 8064;    // tail0 proj rows (8000 -> 8064)
    const int N1_P  = 40064;   // tail1 proj rows (40000 -> 40064)

    size_t off = 0;
    auto alloc = [&](size_t bytes) { size_t o = off; off += (bytes + 255) & ~(size_t)255; return o; };
    ushort* x_bf   = (ushort*)(ws + alloc((size_t)BATCH * DH * 2));
    ushort* Wh_bf  = (ushort*)(ws + alloc((size_t)NH_P * DH * 2));
    ushort* W0a_bf = (ushort*)(ws + alloc((size_t)DH * DH * 2));
    ushort* W0b_bf = (ushort*)(ws + alloc((size_t)N0_P * DH * 2));
    ushort* W1a_bf = (ushort*)(ws + alloc((size_t)256 * DH * 2));
    ushort* W1b_bf = (ushort*)(ws + alloc((size_t)N1_P * 256 * 2));
    ushort* h0_bf  = (ushort*)(ws + alloc((size_t)BATCH * DH * 2));
    ushort* h1_bf  = (ushort*)(ws + alloc((size_t)BATCH * 256 * 2));
    float*  headL  = (float*)(ws + alloc((size_t)BATCH * OUT_HEAD * 4));
    float*  s01    = (float*)(ws + alloc((size_t)BATCH * 2 * 4));
    float*  rs0    = (float*)(ws + alloc((size_t)BATCH * 4));
    float*  rs1    = (float*)(ws + alloc((size_t)BATCH * 4));
    ushort* L0     = (ushort*)(ws + alloc((size_t)BATCH * N0_P * 2));  // tail0 bf16 logits
    ushort* L1     = (ushort*)(ws + alloc((size_t)BATCH * N1_P * 2));  // tail1 bf16 logits

    auto cvt = [&](const float* in, ushort* o, size_t n_src, size_t n_dst) {
        int n4s = (int)(n_src / 4), n4d = (int)(n_dst / 4);
        int blocks = (n4d + 255) / 256;
        if (blocks > 2048) blocks = 2048;
        f2bf_pad_kernel<<<blocks, 256, 0, stream>>>((const float4*)in, (ushort4*)o, n4s, n4d);
    };
    cvt(x,   x_bf,   (size_t)BATCH * DH,        (size_t)BATCH * DH);
    cvt(Wh,  Wh_bf,  (size_t)OUT_HEAD * DH,     (size_t)NH_P * DH);
    cvt(W0a, W0a_bf, (size_t)DH * DH,           (size_t)DH * DH);
    cvt(W0b, W0b_bf, (size_t)(CC1 - CC0) * DH,  (size_t)N0_P * DH);
    cvt(W1a, W1a_bf, (size_t)256 * DH,          (size_t)256 * DH);
    cvt(W1b, W1b_bf, (size_t)(CC2 - CC1) * 256, (size_t)N1_P * 256);

    zero_kernel<<<(BATCH + 255) / 256, 256, 0, stream>>>(rs0, rs1, BATCH);

    // h0 = x @ W0a^T (bf16), h1 = x @ W1a^T (bf16)
    gemm128_kernel<true, false><<<dim3(DH / 128, BATCH / 128), 256, 0, stream>>>(
        x_bf, W0a_bf, h0_bf, BATCH, DH, DH, DH, nullptr);
    gemm128_kernel<true, false><<<dim3(256 / 128, BATCH / 128), 256, 0, stream>>>(
        x_bf, W1a_bf, h1_bf, BATCH, 256, DH, 256, nullptr);
    // head logits (fp32, ws)
    gemm128_kernel<false, false><<<dim3(NH_P / 128, BATCH / 128), 256, 0, stream>>>(
        x_bf, Wh_bf, headL, BATCH, OUT_HEAD, DH, OUT_HEAD, nullptr);
    // head log-softmax -> out[:, :2000] + cluster scalars
    head_lsm_kernel<<<BATCH, 256, 0, stream>>>(headL, bh, out, s01);
    // tail logits (bf16, ws) with fused row sum-of-exp
    gemm128_kernel<true, true><<<dim3(N0_P / 128, BATCH / 128), 256, 0, stream>>>(
        h0_bf, W0b_bf, L0, BATCH, CC1 - CC0, DH, N0_P, rs0);
    gemm128_kernel<true, true><<<dim3(N1_P / 128, BATCH / 128), 256, 0, stream>>>(
        h1_bf, W1b_bf, L1, BATCH, CC2 - CC1, 256, N1_P, rs1);
    // normalize tails: bf16 logits -> fp32 out with additive correction
    finalize_bf16_kernel<<<dim3((1000 + 255) / 256, BATCH), 256, 0, stream>>>(
        L0, N0_P, 1000, out + CC0, rs0, s01, 0);
    finalize_bf16_kernel<<<dim3((5000 + 255) / 256, BATCH), 256, 0, stream>>>(
        L1, N1_P, 5000, out + CC1, rs1, s01, 1);
}